// Round 1
// baseline (2123.549 us; speedup 1.0000x reference)
//
#include <hip/hip_runtime.h>
#include <math.h>

#define NUSER 20000
#define NITEM 20000
#define NNODE 40000

__device__ __forceinline__ float leaky(float v){ return v > 0.0f ? v : 0.01f*v; }

enum { EPI_STORE=0, EPI_TANH=1, EPI_LEAKY_ADD=2, EPI_ACCUM=3 };

// ---------------- GEMM: C = epi(A[M,K] @ W[K,N]) ----------------
template<int BM,int BN,int BK,int TM,int TN,int EPI>
__global__ __launch_bounds__(256)
void gemm_k(const float* __restrict__ A, const float* __restrict__ W,
            const float* __restrict__ bias, const float* __restrict__ add,
            float* __restrict__ C, int M, int N, int K)
{
  __shared__ float As[BK][BM+4];   // transposed A tile, +4 pad: conflict-free strided writes, aligned b128 reads
  __shared__ float Bs[BK][BN+4];
  const int tid = threadIdx.x;
  const int row0 = blockIdx.y*BM, col0 = blockIdx.x*BN;
  constexpr int TX = BN/TN, TY = BM/TM;
  static_assert(TX*TY==256, "thread tile mismatch");
  const int tx = tid % TX, ty = tid / TX;

  float acc[TM][TN];
  #pragma unroll
  for (int i=0;i<TM;i++)
    #pragma unroll
    for (int j=0;j<TN;j++) acc[i][j]=0.f;

  constexpr int A_PER = (BM*BK/4)/256;
  constexpr int B_PER = (BK*BN/4)/256;

  for (int kt=0; kt<K; kt+=BK) {
    #pragma unroll
    for (int i=0;i<A_PER;i++) {
      int f = tid + i*256;
      int r = f/(BK/4);
      int c = (f%(BK/4))*4;
      float4 v = make_float4(0.f,0.f,0.f,0.f);
      int gr = row0 + r, gc = kt + c;
      if (gr < M && gc < K) v = *(const float4*)(A + (size_t)gr*K + gc);  // K%4==0 always
      As[c+0][r]=v.x; As[c+1][r]=v.y; As[c+2][r]=v.z; As[c+3][r]=v.w;
    }
    #pragma unroll
    for (int i=0;i<B_PER;i++) {
      int f = tid + i*256;
      int r = f/(BN/4);
      int c = (f%(BN/4))*4;
      float4 v = make_float4(0.f,0.f,0.f,0.f);
      int gr = kt + r, gc = col0 + c;
      if (gr < K && gc < N) v = *(const float4*)(W + (size_t)gr*N + gc);  // N%4==0 always
      *(float4*)&Bs[r][c] = v;
    }
    __syncthreads();
    #pragma unroll
    for (int k=0;k<BK;k++) {
      float af[TM], bf[TN];
      #pragma unroll
      for (int i=0;i<TM;i+=4) *(float4*)&af[i] = *(const float4*)&As[k][ty*TM+i];
      #pragma unroll
      for (int j=0;j<TN;j+=4) *(float4*)&bf[j] = *(const float4*)&Bs[k][tx*TN+j];
      #pragma unroll
      for (int i=0;i<TM;i++)
        #pragma unroll
        for (int j=0;j<TN;j++)
          acc[i][j] = fmaf(af[i], bf[j], acc[i][j]);
    }
    __syncthreads();
  }
  #pragma unroll
  for (int i=0;i<TM;i++) {
    int r = row0 + ty*TM + i;
    if (r >= M) continue;
    #pragma unroll
    for (int j=0;j<TN;j++) {
      int c = col0 + tx*TN + j;
      if (c >= N) continue;
      size_t idx = (size_t)r*N + c;
      float v = acc[i][j];
      if (EPI==EPI_STORE)          C[idx] = v;
      else if (EPI==EPI_TANH)      C[idx] = tanhf(v + bias[c]);
      else if (EPI==EPI_LEAKY_ADD) C[idx] = leaky(v + bias[c]) + add[idx];
      else /* EPI_ACCUM */         C[idx] += leaky(v + bias[c] + add[idx]);
    }
  }
}

// ---------------- graph structure ----------------
// doubled edges: for e in [0,2E): src(e) = ei[e]; dst(e) = e<E ? ei[e+E] : ei[e-E]
__global__ void count_deg(const int* __restrict__ ei, int* __restrict__ deg, int E)
{
  int e = blockIdx.x*blockDim.x + threadIdx.x;
  if (e >= 2*E) return;
  int dst = (e < E) ? ei[e+E] : ei[e-E];
  atomicAdd(&deg[dst], 1);
}

__global__ void scan_rowptr(const int* __restrict__ deg, int* __restrict__ row_ptr, int n)
{
  __shared__ int sm[256];
  __shared__ int carry;
  int tid = threadIdx.x;
  if (tid==0) carry = 0;
  __syncthreads();
  for (int base=0; base<n; base+=256) {
    int idx = base + tid;
    int v = (idx < n) ? deg[idx] : 0;
    sm[tid] = v; __syncthreads();
    #pragma unroll
    for (int off=1; off<256; off<<=1) {
      int t = (tid >= off) ? sm[tid-off] : 0;
      __syncthreads();
      sm[tid] += t;
      __syncthreads();
    }
    if (idx < n) row_ptr[idx+1] = carry + sm[tid];
    __syncthreads();
    if (tid==255) carry += sm[255];
    __syncthreads();
  }
  if (tid==0) row_ptr[0] = 0;
}

__global__ void fill_csr(const int* __restrict__ ei, const int* __restrict__ row_ptr,
                         int* __restrict__ row_fill, int* __restrict__ col_src,
                         int* __restrict__ col_eid, int E)
{
  int e = blockIdx.x*blockDim.x + threadIdx.x;
  if (e >= 2*E) return;
  int src = ei[e];
  int dst = (e < E) ? ei[e+E] : ei[e-E];
  int pos = row_ptr[dst] + atomicAdd(&row_fill[dst], 1);
  col_src[pos] = src;
  col_eid[pos] = e;
}

// ---------------- per-modality kernels ----------------
__global__ void l2norm_rows(float* __restrict__ x, int rows, int L)
{
  int wave = (blockIdx.x*blockDim.x + threadIdx.x) >> 6;
  int lane = threadIdx.x & 63;
  if (wave >= rows) return;
  float* row = x + (size_t)wave*L;
  float ss = 0.f;
  for (int c=lane;c<L;c+=64) { float v = row[c]; ss += v*v; }
  #pragma unroll
  for (int o=32;o;o>>=1) ss += __shfl_xor(ss, o);
  float inv = 1.0f / fmaxf(sqrtf(ss), 1e-12f);
  for (int c=lane;c<L;c+=64) row[c] *= inv;
}

// per-edge: inner = xw[dst].xw[src]; gate = sigmoid(inner/sqrt(deg[src])); logits = inner*gate
__global__ __launch_bounds__(256)
void edge_logits_k(const float* __restrict__ xw, const int* __restrict__ ei,
                   const int* __restrict__ deg, float* __restrict__ logits, int L, int E)
{
  int g = (blockIdx.x*blockDim.x + threadIdx.x) >> 4;
  int lane = threadIdx.x & 15;
  if (g >= 2*E) return;
  int src = ei[g];
  int dst = (g < E) ? ei[g+E] : ei[g-E];
  const float4* pi = (const float4*)(xw + (size_t)dst*L);
  const float4* pj = (const float4*)(xw + (size_t)src*L);
  int L4 = L >> 2;
  float s = 0.f;
  for (int c=lane;c<L4;c+=16) {
    float4 a = pi[c], b = pj[c];
    s += a.x*b.x + a.y*b.y + a.z*b.z + a.w*b.w;
  }
  #pragma unroll
  for (int o=8;o;o>>=1) s += __shfl_xor(s, o, 16);
  if (lane==0) {
    float t = s / sqrtf((float)deg[src]);
    float gate = 1.0f/(1.0f + expf(-t));
    logits[g] = s * gate;
  }
}

// per-dst-node softmax over in-edges -> alpha in CSR order
__global__ void node_softmax(const float* __restrict__ logits, const int* __restrict__ row_ptr,
                             const int* __restrict__ col_eid, float* __restrict__ alpha, int n)
{
  int node = blockIdx.x*blockDim.x + threadIdx.x;
  if (node >= n) return;
  int s = row_ptr[node], e = row_ptr[node+1];
  if (s == e) return;
  float m = -INFINITY;
  for (int p=s;p<e;p++) m = fmaxf(m, logits[col_eid[p]]);
  float d = 0.f;
  for (int p=s;p<e;p++) d += expf(logits[col_eid[p]] - m);
  d = fmaxf(d, 1e-16f);
  for (int p=s;p<e;p++) alpha[p] = expf(logits[col_eid[p]] - m) / d;
}

// per-node: h = leaky(l2norm(sum_e alpha_e * xw[src_e] + bias)); one wave per node
__global__ __launch_bounds__(256)
void aggregate_k(const float* __restrict__ xw, const float* __restrict__ alpha,
                 const int* __restrict__ row_ptr, const int* __restrict__ col_src,
                 const float* __restrict__ bias, float* __restrict__ h, int n, int L)
{
  int node = (blockIdx.x*blockDim.x + threadIdx.x) >> 6;
  int lane = threadIdx.x & 63;
  if (node >= n) return;
  float acc[4] = {0.f,0.f,0.f,0.f};
  int s = row_ptr[node], e = row_ptr[node+1];
  for (int p=s;p<e;p++) {
    float a = alpha[p];
    const float* srcrow = xw + (size_t)col_src[p]*L;
    int i=0;
    for (int c=lane;c<L;c+=64,i++) acc[i] = fmaf(a, srcrow[c], acc[i]);
  }
  float ss = 0.f;
  { int i=0; for (int c=lane;c<L;c+=64,i++) { acc[i] += bias[c]; ss += acc[i]*acc[i]; } }
  #pragma unroll
  for (int o=32;o;o>>=1) ss += __shfl_xor(ss, o);
  float inv = 1.0f / fmaxf(sqrtf(ss), 1e-12f);
  { int i=0; for (int c=lane;c<L;c+=64,i++) h[(size_t)node*L + c] = leaky(acc[i]*inv); }
}

// scores: out[0..1024)=pos, [1024..2048)=neg; rep holds 3*rep_true -> scale dot by 1/9
__global__ __launch_bounds__(256)
void score_k(const float* __restrict__ rep, const int* __restrict__ un,
             const int* __restrict__ pi, const int* __restrict__ ni, float* __restrict__ out)
{
  int wid = (blockIdx.x*blockDim.x + threadIdx.x) >> 6;
  int lane = threadIdx.x & 63;
  if (wid >= 2048) return;
  int i = wid & 1023;
  int isneg = wid >> 10;
  int u = un[i];
  int it = isneg ? ni[i] : pi[i];
  float p = rep[(size_t)u*64 + lane] * rep[(size_t)it*64 + lane];
  #pragma unroll
  for (int o=32;o;o>>=1) p += __shfl_xor(p, o);
  if (lane==0) out[isneg*1024 + i] = p * (1.0f/9.0f);
}

// ---------------- launch ----------------
static inline size_t align_up(size_t v){ return (v + 255) & ~(size_t)255; }
static inline int cdiv(int a, int b){ return (a + b - 1) / b; }

extern "C" void kernel_launch(void* const* d_in, const int* in_sizes, int n_in,
                              void* d_out, int out_size, void* d_ws, size_t ws_size,
                              hipStream_t stream)
{
  const int E  = in_sizes[31] / 2;   // 250000
  const int E2 = 2*E;

  // workspace carve
  char* p = (char*)d_ws;
  auto carve = [&](size_t bytes){ char* r = p; p += align_up(bytes); return r; };
  float* x      = (float*)carve((size_t)NNODE*256*4);  // also reused as h
  float* xw     = (float*)carve((size_t)NNODE*256*4);
  float* xhat   = (float*)carve((size_t)NNODE*64*4);
  float* rep    = (float*)carve((size_t)NNODE*64*4);
  float* logits = (float*)carve((size_t)E2*4);
  float* alpha  = (float*)carve((size_t)E2*4);
  int* deg      = (int*)carve((size_t)NNODE*4);
  int* row_ptr  = (int*)carve((size_t)(NNODE+1)*4);
  int* row_fill = (int*)carve((size_t)NNODE*4);
  int* col_src  = (int*)carve((size_t)E2*4);
  int* col_eid  = (int*)carve((size_t)E2*4);

  const int* ei = (const int*)d_in[31];
  const float* id_emb = (const float*)d_in[30];

  hipMemsetAsync(deg, 0, (size_t)NNODE*4, stream);
  hipMemsetAsync(row_fill, 0, (size_t)NNODE*4, stream);
  hipMemsetAsync(rep, 0, (size_t)NNODE*64*4, stream);

  {
    int blocks = cdiv(E2, 256);
    count_deg<<<blocks,256,0,stream>>>(ei, deg, E);
    scan_rowptr<<<1,256,0,stream>>>(deg, row_ptr, NNODE);
    fill_csr<<<blocks,256,0,stream>>>(ei, row_ptr, row_fill, col_src, col_eid, E);
  }

  struct Mod { const float *feat,*pref,*mlp_w,*mlp_b,*conv_w,*conv_b,*lin_w,*lin_b,*g_w,*g_b; int Fd, L; };
  Mod mods[3];
  for (int m=0;m<3;m++) {
    int b = m*10;
    mods[m].feat   = (const float*)d_in[b+0];
    mods[m].pref   = (const float*)d_in[b+1];
    mods[m].mlp_w  = (const float*)d_in[b+2];
    mods[m].mlp_b  = (const float*)d_in[b+3];
    mods[m].conv_w = (const float*)d_in[b+4];
    mods[m].conv_b = (const float*)d_in[b+5];
    mods[m].lin_w  = (const float*)d_in[b+6];
    mods[m].lin_b  = (const float*)d_in[b+7];
    mods[m].g_w    = (const float*)d_in[b+8];
    mods[m].g_b    = (const float*)d_in[b+9];
  }
  mods[0].Fd = 2048; mods[0].L = 256;
  mods[1].Fd = 128;  mods[1].L = 128;
  mods[2].Fd = 100;  mods[2].L = 100;

  for (int m=0;m<3;m++) {
    const Mod& md = mods[m];
    const int L = md.L, Fd = md.Fd;

    // x[0:NUSER) = pref ; x[NUSER:NNODE) = tanh(feat @ mlp_w + b) ; then row-l2norm
    hipMemcpyAsync(x, md.pref, (size_t)NUSER*L*4, hipMemcpyDeviceToDevice, stream);
    {
      dim3 g(cdiv(L,128), cdiv(NUSER,128));
      gemm_k<128,128,16,8,8,EPI_TANH><<<g,256,0,stream>>>(md.feat, md.mlp_w, md.mlp_b, nullptr,
                                                          x + (size_t)NUSER*L, NUSER, L, Fd);
    }
    l2norm_rows<<<cdiv(NNODE,4),256,0,stream>>>(x, NNODE, L);

    // xw = x @ conv_w
    {
      dim3 g(cdiv(L,128), cdiv(NNODE,128));
      gemm_k<128,128,16,8,8,EPI_STORE><<<g,256,0,stream>>>(x, md.conv_w, nullptr, nullptr,
                                                           xw, NNODE, L, L);
    }
    // xhat = leaky(x @ lin_w + lin_b) + id_emb
    {
      dim3 g(1, cdiv(NNODE,128));
      gemm_k<128,64,16,8,4,EPI_LEAKY_ADD><<<g,256,0,stream>>>(x, md.lin_w, md.lin_b, id_emb,
                                                              xhat, NNODE, 64, L);
    }
    // GAT edge phase
    edge_logits_k<<<cdiv(E2*16,256),256,0,stream>>>(xw, ei, deg, logits, L, E);
    node_softmax<<<cdiv(NNODE,256),256,0,stream>>>(logits, row_ptr, col_eid, alpha, NNODE);
    aggregate_k<<<cdiv(NNODE,4),256,0,stream>>>(xw, alpha, row_ptr, col_src, md.conv_b,
                                                x /* h overwrites x */, NNODE, L);
    // rep += leaky(h @ g_w + g_b + xhat)
    {
      dim3 g(1, cdiv(NNODE,128));
      gemm_k<128,64,16,8,4,EPI_ACCUM><<<g,256,0,stream>>>(x, md.g_w, md.g_b, xhat,
                                                          rep, NNODE, 64, L);
    }
  }

  score_k<<<cdiv(2048*64,256),256,0,stream>>>(rep, (const int*)d_in[32], (const int*)d_in[33],
                                              (const int*)d_in[34], (float*)d_out);
}

// Round 2
// 1677.655 us; speedup vs baseline: 1.2658x; 1.2658x over previous
//
#include <hip/hip_runtime.h>
#include <math.h>

#define NUSER 20000
#define NITEM 20000
#define NNODE 40000

__device__ __forceinline__ float leaky(float v){ return v > 0.0f ? v : 0.01f*v; }

enum { EPI_STORE=0, EPI_TANH=1, EPI_LEAKY_ADD=2, EPI_ACCUM=3 };

// ---------------- GEMM: C = epi(A[M,K] @ W[K,N]) ----------------
// 64x64 tile, 256 threads, TM=TN=4: small tile -> many blocks -> occupancy
// (R1: 128x128 tile gave only 314 blocks for v-mlp -> Occupancy 13.8%, VALUBusy 33%)
template<int BM,int BN,int BK,int TM,int TN,int EPI>
__global__ __launch_bounds__(256)
void gemm_k(const float* __restrict__ A, const float* __restrict__ W,
            const float* __restrict__ bias, const float* __restrict__ add,
            float* __restrict__ C, int M, int N, int K)
{
  __shared__ float As[BK][BM+4];   // transposed A tile; +4 pad keeps b128 reads aligned & conflict-free
  __shared__ float Bs[BK][BN+4];
  const int tid = threadIdx.x;
  const int row0 = blockIdx.y*BM, col0 = blockIdx.x*BN;
  constexpr int TX = BN/TN, TY = BM/TM;
  static_assert(TX*TY==256, "thread tile mismatch");
  const int tx = tid % TX, ty = tid / TX;

  float acc[TM][TN];
  #pragma unroll
  for (int i=0;i<TM;i++)
    #pragma unroll
    for (int j=0;j<TN;j++) acc[i][j]=0.f;

  constexpr int A_PER = (BM*BK/4)/256;
  constexpr int B_PER = (BK*BN/4)/256;

  for (int kt=0; kt<K; kt+=BK) {
    #pragma unroll
    for (int i=0;i<A_PER;i++) {
      int f = tid + i*256;
      int r = f/(BK/4);
      int c = (f%(BK/4))*4;
      float4 v = make_float4(0.f,0.f,0.f,0.f);
      int gr = row0 + r, gc = kt + c;
      if (gr < M && gc < K) v = *(const float4*)(A + (size_t)gr*K + gc);  // K%4==0 always
      As[c+0][r]=v.x; As[c+1][r]=v.y; As[c+2][r]=v.z; As[c+3][r]=v.w;
    }
    #pragma unroll
    for (int i=0;i<B_PER;i++) {
      int f = tid + i*256;
      int r = f/(BN/4);
      int c = (f%(BN/4))*4;
      float4 v = make_float4(0.f,0.f,0.f,0.f);
      int gr = kt + r, gc = col0 + c;
      if (gr < K && gc < N) v = *(const float4*)(W + (size_t)gr*N + gc);  // N%4==0 always
      *(float4*)&Bs[r][c] = v;
    }
    __syncthreads();
    #pragma unroll
    for (int k=0;k<BK;k++) {
      float af[TM], bf[TN];
      #pragma unroll
      for (int i=0;i<TM;i+=4) *(float4*)&af[i] = *(const float4*)&As[k][ty*TM+i];
      #pragma unroll
      for (int j=0;j<TN;j+=4) *(float4*)&bf[j] = *(const float4*)&Bs[k][tx*TN+j];
      #pragma unroll
      for (int i=0;i<TM;i++)
        #pragma unroll
        for (int j=0;j<TN;j++)
          acc[i][j] = fmaf(af[i], bf[j], acc[i][j]);
    }
    __syncthreads();
  }
  #pragma unroll
  for (int i=0;i<TM;i++) {
    int r = row0 + ty*TM + i;
    if (r >= M) continue;
    #pragma unroll
    for (int j=0;j<TN;j++) {
      int c = col0 + tx*TN + j;
      if (c >= N) continue;
      size_t idx = (size_t)r*N + c;
      float v = acc[i][j];
      if (EPI==EPI_STORE)          C[idx] = v;
      else if (EPI==EPI_TANH)      C[idx] = tanhf(v + bias[c]);
      else if (EPI==EPI_LEAKY_ADD) C[idx] = leaky(v + bias[c]) + add[idx];
      else /* EPI_ACCUM */         C[idx] += leaky(v + bias[c] + add[idx]);
    }
  }
}

// ---------------- graph structure ----------------
// doubled edges: for e in [0,2E): src(e) = ei[e]; dst(e) = e<E ? ei[e+E] : ei[e-E]
__global__ void count_deg(const int* __restrict__ ei, int* __restrict__ deg, int E)
{
  int e = blockIdx.x*blockDim.x + threadIdx.x;
  if (e >= 2*E) return;
  int dst = (e < E) ? ei[e+E] : ei[e-E];
  atomicAdd(&deg[dst], 1);
}

__global__ void scan_rowptr(const int* __restrict__ deg, int* __restrict__ row_ptr, int n)
{
  __shared__ int sm[256];
  __shared__ int carry;
  int tid = threadIdx.x;
  if (tid==0) carry = 0;
  __syncthreads();
  for (int base=0; base<n; base+=256) {
    int idx = base + tid;
    int v = (idx < n) ? deg[idx] : 0;
    sm[tid] = v; __syncthreads();
    #pragma unroll
    for (int off=1; off<256; off<<=1) {
      int t = (tid >= off) ? sm[tid-off] : 0;
      __syncthreads();
      sm[tid] += t;
      __syncthreads();
    }
    if (idx < n) row_ptr[idx+1] = carry + sm[tid];
    __syncthreads();
    if (tid==255) carry += sm[255];
    __syncthreads();
  }
  if (tid==0) row_ptr[0] = 0;
}

__global__ void fill_csr(const int* __restrict__ ei, const int* __restrict__ row_ptr,
                         int* __restrict__ row_fill, int* __restrict__ col_src,
                         int* __restrict__ col_eid, int E)
{
  int e = blockIdx.x*blockDim.x + threadIdx.x;
  if (e >= 2*E) return;
  int src = ei[e];
  int dst = (e < E) ? ei[e+E] : ei[e-E];
  int pos = row_ptr[dst] + atomicAdd(&row_fill[dst], 1);
  col_src[pos] = src;
  col_eid[pos] = e;
}

// ---------------- per-modality kernels ----------------
__global__ void l2norm_rows(float* __restrict__ x, int rows, int L)
{
  int wave = (blockIdx.x*blockDim.x + threadIdx.x) >> 6;
  int lane = threadIdx.x & 63;
  if (wave >= rows) return;
  float* row = x + (size_t)wave*L;
  float ss = 0.f;
  for (int c=lane;c<L;c+=64) { float v = row[c]; ss += v*v; }
  #pragma unroll
  for (int o=32;o;o>>=1) ss += __shfl_xor(ss, o);
  float inv = 1.0f / fmaxf(sqrtf(ss), 1e-12f);
  for (int c=lane;c<L;c+=64) row[c] *= inv;
}

// per-edge: inner = xw[dst].xw[src]; gate = sigmoid(inner/sqrt(deg[src])); logits = inner*gate
__global__ __launch_bounds__(256)
void edge_logits_k(const float* __restrict__ xw, const int* __restrict__ ei,
                   const int* __restrict__ deg, float* __restrict__ logits, int L, int E)
{
  int g = (blockIdx.x*blockDim.x + threadIdx.x) >> 4;
  int lane = threadIdx.x & 15;
  if (g >= 2*E) return;
  int src = ei[g];
  int dst = (g < E) ? ei[g+E] : ei[g-E];
  const float4* pi = (const float4*)(xw + (size_t)dst*L);
  const float4* pj = (const float4*)(xw + (size_t)src*L);
  int L4 = L >> 2;
  float s = 0.f;
  for (int c=lane;c<L4;c+=16) {
    float4 a = pi[c], b = pj[c];
    s += a.x*b.x + a.y*b.y + a.z*b.z + a.w*b.w;
  }
  #pragma unroll
  for (int o=8;o;o>>=1) s += __shfl_xor(s, o, 16);
  if (lane==0) {
    float t = s / sqrtf((float)deg[src]);
    float gate = 1.0f/(1.0f + expf(-t));
    logits[g] = s * gate;
  }
}

// per-dst-node softmax over in-edges -> alpha in CSR order. One wave per node;
// logits cached in regs for deg<=256 (avg deg 25), streamed fallback otherwise.
__global__ __launch_bounds__(256)
void node_softmax(const float* __restrict__ logits, const int* __restrict__ row_ptr,
                  const int* __restrict__ col_eid, float* __restrict__ alpha, int n)
{
  int node = (blockIdx.x*blockDim.x + threadIdx.x) >> 6;
  int lane = threadIdx.x & 63;
  if (node >= n) return;
  int s = row_ptr[node], e = row_ptr[node+1];
  int cnt = e - s;
  if (cnt == 0) return;
  float m = -INFINITY;
  if (cnt <= 256) {
    float lv[4];
    int ni = (cnt + 63) >> 6;
    #pragma unroll 4
    for (int i=0;i<ni;i++) {
      int p = s + lane + i*64;
      lv[i] = (p < e) ? logits[col_eid[p]] : -INFINITY;
      m = fmaxf(m, lv[i]);
    }
    #pragma unroll
    for (int o=32;o;o>>=1) m = fmaxf(m, __shfl_xor(m, o));
    float d = 0.f;
    #pragma unroll 4
    for (int i=0;i<ni;i++) {
      int p = s + lane + i*64;
      if (p < e) { lv[i] = expf(lv[i]-m); d += lv[i]; }
    }
    #pragma unroll
    for (int o=32;o;o>>=1) d += __shfl_xor(d, o);
    float inv = 1.0f / fmaxf(d, 1e-16f);
    #pragma unroll 4
    for (int i=0;i<ni;i++) {
      int p = s + lane + i*64;
      if (p < e) alpha[p] = lv[i]*inv;
    }
  } else {
    for (int p=s+lane;p<e;p+=64) m = fmaxf(m, logits[col_eid[p]]);
    #pragma unroll
    for (int o=32;o;o>>=1) m = fmaxf(m, __shfl_xor(m, o));
    float d = 0.f;
    for (int p=s+lane;p<e;p+=64) d += expf(logits[col_eid[p]]-m);
    #pragma unroll
    for (int o=32;o;o>>=1) d += __shfl_xor(d, o);
    float inv = 1.0f / fmaxf(d, 1e-16f);
    for (int p=s+lane;p<e;p+=64) alpha[p] = expf(logits[col_eid[p]]-m)*inv;
  }
}

// per-node: h = leaky(l2norm(sum_e alpha_e * xw[src_e] + bias)); one wave per node.
// VW: elements per lane (4 for L=256, 2 for L=128/100) -> one vector load per edge.
template<int VW>
__global__ __launch_bounds__(256)
void aggregate_k(const float* __restrict__ xw, const float* __restrict__ alpha,
                 const int* __restrict__ row_ptr, const int* __restrict__ col_src,
                 const float* __restrict__ bias, float* __restrict__ h, int n, int L)
{
  int node = (blockIdx.x*blockDim.x + threadIdx.x) >> 6;
  int lane = threadIdx.x & 63;
  if (node >= n) return;
  int s = row_ptr[node], e = row_ptr[node+1];
  const int c0 = lane*VW;
  const bool act = c0 < L;
  float acc[VW];
  #pragma unroll
  for (int j=0;j<VW;j++) acc[j]=0.f;
  for (int p=s;p<e;p++) {
    float a = alpha[p];
    const float* row = xw + (size_t)col_src[p]*L + c0;
    if (act) {
      if constexpr (VW==4) {
        float4 v = *(const float4*)row;
        acc[0]=fmaf(a,v.x,acc[0]); acc[1]=fmaf(a,v.y,acc[1]);
        acc[2]=fmaf(a,v.z,acc[2]); acc[3]=fmaf(a,v.w,acc[3]);
      } else if constexpr (VW==2) {
        float2 v = *(const float2*)row;
        acc[0]=fmaf(a,v.x,acc[0]); acc[1]=fmaf(a,v.y,acc[1]);
      } else {
        acc[0]=fmaf(a,row[0],acc[0]);
      }
    }
  }
  float ss = 0.f;
  if (act) {
    #pragma unroll
    for (int j=0;j<VW;j++) { acc[j] += bias[c0+j]; ss += acc[j]*acc[j]; }
  }
  #pragma unroll
  for (int o=32;o;o>>=1) ss += __shfl_xor(ss, o);
  float inv = 1.0f / fmaxf(sqrtf(ss), 1e-12f);
  if (act) {
    #pragma unroll
    for (int j=0;j<VW;j++) h[(size_t)node*L + c0 + j] = leaky(acc[j]*inv);
  }
}

// scores: out[0..1024)=pos, [1024..2048)=neg; rep holds 3*rep_true -> scale dot by 1/9
__global__ __launch_bounds__(256)
void score_k(const float* __restrict__ rep, const int* __restrict__ un,
             const int* __restrict__ pi, const int* __restrict__ ni, float* __restrict__ out)
{
  int wid = (blockIdx.x*blockDim.x + threadIdx.x) >> 6;
  int lane = threadIdx.x & 63;
  if (wid >= 2048) return;
  int i = wid & 1023;
  int isneg = wid >> 10;
  int u = un[i];
  int it = isneg ? ni[i] : pi[i];
  float p = rep[(size_t)u*64 + lane] * rep[(size_t)it*64 + lane];
  #pragma unroll
  for (int o=32;o;o>>=1) p += __shfl_xor(p, o);
  if (lane==0) out[isneg*1024 + i] = p * (1.0f/9.0f);
}

// ---------------- launch ----------------
static inline size_t align_up(size_t v){ return (v + 255) & ~(size_t)255; }
static inline int cdiv(int a, int b){ return (a + b - 1) / b; }

extern "C" void kernel_launch(void* const* d_in, const int* in_sizes, int n_in,
                              void* d_out, int out_size, void* d_ws, size_t ws_size,
                              hipStream_t stream)
{
  const int E  = in_sizes[31] / 2;   // 250000
  const int E2 = 2*E;

  // workspace carve
  char* p = (char*)d_ws;
  auto carve = [&](size_t bytes){ char* r = p; p += align_up(bytes); return r; };
  float* x      = (float*)carve((size_t)NNODE*256*4);  // also reused as h
  float* xw     = (float*)carve((size_t)NNODE*256*4);
  float* xhat   = (float*)carve((size_t)NNODE*64*4);
  float* rep    = (float*)carve((size_t)NNODE*64*4);
  float* logits = (float*)carve((size_t)E2*4);
  float* alpha  = (float*)carve((size_t)E2*4);
  int* deg      = (int*)carve((size_t)NNODE*4);
  int* row_ptr  = (int*)carve((size_t)(NNODE+1)*4);
  int* row_fill = (int*)carve((size_t)NNODE*4);
  int* col_src  = (int*)carve((size_t)E2*4);
  int* col_eid  = (int*)carve((size_t)E2*4);

  const int* ei = (const int*)d_in[31];
  const float* id_emb = (const float*)d_in[30];

  hipMemsetAsync(deg, 0, (size_t)NNODE*4, stream);
  hipMemsetAsync(row_fill, 0, (size_t)NNODE*4, stream);
  hipMemsetAsync(rep, 0, (size_t)NNODE*64*4, stream);

  {
    int blocks = cdiv(E2, 256);
    count_deg<<<blocks,256,0,stream>>>(ei, deg, E);
    scan_rowptr<<<1,256,0,stream>>>(deg, row_ptr, NNODE);
    fill_csr<<<blocks,256,0,stream>>>(ei, row_ptr, row_fill, col_src, col_eid, E);
  }

  struct Mod { const float *feat,*pref,*mlp_w,*mlp_b,*conv_w,*conv_b,*lin_w,*lin_b,*g_w,*g_b; int Fd, L; };
  Mod mods[3];
  for (int m=0;m<3;m++) {
    int b = m*10;
    mods[m].feat   = (const float*)d_in[b+0];
    mods[m].pref   = (const float*)d_in[b+1];
    mods[m].mlp_w  = (const float*)d_in[b+2];
    mods[m].mlp_b  = (const float*)d_in[b+3];
    mods[m].conv_w = (const float*)d_in[b+4];
    mods[m].conv_b = (const float*)d_in[b+5];
    mods[m].lin_w  = (const float*)d_in[b+6];
    mods[m].lin_b  = (const float*)d_in[b+7];
    mods[m].g_w    = (const float*)d_in[b+8];
    mods[m].g_b    = (const float*)d_in[b+9];
  }
  mods[0].Fd = 2048; mods[0].L = 256;
  mods[1].Fd = 128;  mods[1].L = 128;
  mods[2].Fd = 100;  mods[2].L = 100;

  for (int m=0;m<3;m++) {
    const Mod& md = mods[m];
    const int L = md.L, Fd = md.Fd;

    // x[0:NUSER) = pref ; x[NUSER:NNODE) = tanh(feat @ mlp_w + b) ; then row-l2norm
    hipMemcpyAsync(x, md.pref, (size_t)NUSER*L*4, hipMemcpyDeviceToDevice, stream);
    {
      dim3 g(cdiv(L,64), cdiv(NUSER,64));
      gemm_k<64,64,16,4,4,EPI_TANH><<<g,256,0,stream>>>(md.feat, md.mlp_w, md.mlp_b, nullptr,
                                                        x + (size_t)NUSER*L, NUSER, L, Fd);
    }
    l2norm_rows<<<cdiv(NNODE,4),256,0,stream>>>(x, NNODE, L);

    // xw = x @ conv_w
    {
      dim3 g(cdiv(L,64), cdiv(NNODE,64));
      gemm_k<64,64,16,4,4,EPI_STORE><<<g,256,0,stream>>>(x, md.conv_w, nullptr, nullptr,
                                                         xw, NNODE, L, L);
    }
    // xhat = leaky(x @ lin_w + lin_b) + id_emb
    {
      dim3 g(1, cdiv(NNODE,64));
      gemm_k<64,64,16,4,4,EPI_LEAKY_ADD><<<g,256,0,stream>>>(x, md.lin_w, md.lin_b, id_emb,
                                                             xhat, NNODE, 64, L);
    }
    // GAT edge phase
    edge_logits_k<<<cdiv(E2*16,256),256,0,stream>>>(xw, ei, deg, logits, L, E);
    node_softmax<<<cdiv(NNODE*64,256),256,0,stream>>>(logits, row_ptr, col_eid, alpha, NNODE);
    if (L == 256)
      aggregate_k<4><<<cdiv(NNODE*64,256),256,0,stream>>>(xw, alpha, row_ptr, col_src, md.conv_b,
                                                          x /* h overwrites x */, NNODE, L);
    else
      aggregate_k<2><<<cdiv(NNODE*64,256),256,0,stream>>>(xw, alpha, row_ptr, col_src, md.conv_b,
                                                          x, NNODE, L);
    // rep += leaky(h @ g_w + g_b + xhat)
    {
      dim3 g(1, cdiv(NNODE,64));
      gemm_k<64,64,16,4,4,EPI_ACCUM><<<g,256,0,stream>>>(x, md.g_w, md.g_b, xhat,
                                                         rep, NNODE, 64, L);
    }
  }

  score_k<<<cdiv(2048*64,256),256,0,stream>>>(rep, (const int*)d_in[32], (const int*)d_in[33],
                                              (const int*)d_in[34], (float*)d_out);
}

// Round 3
// 1475.507 us; speedup vs baseline: 1.4392x; 1.1370x over previous
//
#include <hip/hip_runtime.h>
#include <math.h>

#define NUSER 20000
#define NITEM 20000
#define NNODE 40000
#define MP_USER 20096   // 157*128
#define MP_NODE 40064   // 313*128

typedef unsigned short u16;
typedef __attribute__((ext_vector_type(8))) short bf16x8;   // 8 bf16 = 4 VGPRs (guide §3)
typedef __attribute__((ext_vector_type(4))) float f32x4;

__device__ __forceinline__ float leaky(float v){ return v > 0.0f ? v : 0.01f*v; }
__device__ __forceinline__ u16 f2bf(float f){
  unsigned u = __float_as_uint(f);
  return (u16)((u + 0x7FFFu + ((u>>16)&1u)) >> 16);   // round-to-nearest-even bf16
}
__device__ __forceinline__ float bf2f(u16 h){ return __uint_as_float(((unsigned)h)<<16); }
__device__ __forceinline__ unsigned pack2(u16 a, u16 b){ return (unsigned)a | ((unsigned)b<<16); }

enum { EPI_STORE=0, EPI_TANH=1, EPI_LEAKY_ADD=2, EPI_ACCUM=3 };

// ================= MFMA GEMM: C[M,N] fp32 = epi(A[M,K] @ W[K,N]) =================
// bf16x3 split: ab ~= ah*bh + ah*bl + al*bh (drops al*bl, ~2^-18 rel).
// Block 128x64, BK=32, 4 waves in 2x2, wave tile 64x32 = 4x2 mfma_16x16x32 tiles.
// ASPLIT: A pre-split bf16 [gridM*128][Kp] (padded, no guards). else fp32 A with guards, cvt in staging.
// B: Wt_hi/Wt_lo bf16 [Np][Kp], transposed + zero-padded (no guards).
template<int EPI, bool ASPLIT>
__global__ __launch_bounds__(256)
void mgemm_k(const float* __restrict__ A, const u16* __restrict__ Ah, const u16* __restrict__ Al,
             const u16* __restrict__ Bh, const u16* __restrict__ Bl,
             const float* __restrict__ bias, const float* __restrict__ add,
             float* __restrict__ C, int M, int N, int K, int Kp)
{
  __shared__ u16 Ash[128][32], Asl[128][32], Bsh[64][32], Bsl[64][32];  // 24 KB
  const int tid = threadIdx.x;
  const int lane = tid & 63, wid = tid >> 6;
  const int wrow = wid & 1, wcol = wid >> 1;
  const int row0 = blockIdx.y*128, col0 = blockIdx.x*64;

  f32x4 acc[4][2] = {};

  for (int kt = 0; kt < Kp; kt += 32) {
    // ---- stage A (512 granules of 8 elems; thread does 2) ----
    #pragma unroll
    for (int i=0;i<2;i++) {
      int g = tid + i*256;
      int r = g >> 2, kp8 = (g & 3)*8;
      if (ASPLIT) {
        size_t ofs = (size_t)(row0 + r)*Kp + kt + kp8;
        *(uint4*)&Ash[r][kp8] = *(const uint4*)(Ah + ofs);
        *(uint4*)&Asl[r][kp8] = *(const uint4*)(Al + ofs);
      } else {
        float fv[8];
        int gr = row0 + r, gk = kt + kp8;
        if (gr < M && gk + 8 <= K) {            // K%4==0 for all our shapes -> aligned float4
          *(float4*)&fv[0] = *(const float4*)(A + (size_t)gr*K + gk);
          *(float4*)&fv[4] = *(const float4*)(A + (size_t)gr*K + gk + 4);
        } else {
          #pragma unroll
          for (int j=0;j<8;j++) fv[j] = (gr < M && gk + j < K) ? A[(size_t)gr*K + gk + j] : 0.f;
        }
        u16 hs[8], ls[8];
        #pragma unroll
        for (int j=0;j<8;j++){ u16 h = f2bf(fv[j]); hs[j]=h; ls[j]=f2bf(fv[j]-bf2f(h)); }
        uint4 hv, lv;
        hv.x=pack2(hs[0],hs[1]); hv.y=pack2(hs[2],hs[3]); hv.z=pack2(hs[4],hs[5]); hv.w=pack2(hs[6],hs[7]);
        lv.x=pack2(ls[0],ls[1]); lv.y=pack2(ls[2],ls[3]); lv.z=pack2(ls[4],ls[5]); lv.w=pack2(ls[6],ls[7]);
        *(uint4*)&Ash[r][kp8] = hv;
        *(uint4*)&Asl[r][kp8] = lv;
      }
    }
    // ---- stage B (256 granules) ----
    {
      int r = tid >> 2, kp8 = (tid & 3)*8;
      size_t ofs = (size_t)(col0 + r)*Kp + kt + kp8;
      *(uint4*)&Bsh[r][kp8] = *(const uint4*)(Bh + ofs);
      *(uint4*)&Bsl[r][kp8] = *(const uint4*)(Bl + ofs);
    }
    __syncthreads();
    // ---- frags + MFMA ----
    const int fr = lane & 15, kg8 = (lane >> 4)*8;   // A/B: 8 contiguous k per lane
    bf16x8 ah[4], al[4], bh[2], bl[2];
    #pragma unroll
    for (int mi=0;mi<4;mi++){
      ah[mi] = *(const bf16x8*)&Ash[wrow*64 + mi*16 + fr][kg8];
      al[mi] = *(const bf16x8*)&Asl[wrow*64 + mi*16 + fr][kg8];
    }
    #pragma unroll
    for (int ni=0;ni<2;ni++){
      bh[ni] = *(const bf16x8*)&Bsh[wcol*32 + ni*16 + fr][kg8];
      bl[ni] = *(const bf16x8*)&Bsl[wcol*32 + ni*16 + fr][kg8];
    }
    #pragma unroll
    for (int mi=0;mi<4;mi++)
      #pragma unroll
      for (int ni=0;ni<2;ni++){
        acc[mi][ni] = __builtin_amdgcn_mfma_f32_16x16x32_bf16(ah[mi], bh[ni], acc[mi][ni], 0,0,0);
        acc[mi][ni] = __builtin_amdgcn_mfma_f32_16x16x32_bf16(ah[mi], bl[ni], acc[mi][ni], 0,0,0);
        acc[mi][ni] = __builtin_amdgcn_mfma_f32_16x16x32_bf16(al[mi], bh[ni], acc[mi][ni], 0,0,0);
      }
    __syncthreads();
  }
  // ---- epilogue: D reg r -> row=(lane>>4)*4+r, col=lane&15 (m89-verified) ----
  #pragma unroll
  for (int mi=0;mi<4;mi++){
    #pragma unroll
    for (int ni=0;ni<2;ni++){
      int col = col0 + wcol*32 + ni*16 + (lane & 15);
      if (col >= N) continue;
      #pragma unroll
      for (int r=0;r<4;r++){
        int row = row0 + wrow*64 + mi*16 + (lane>>4)*4 + r;
        if (row >= M) continue;
        size_t idx = (size_t)row*N + col;
        float v = acc[mi][ni][r];
        if (EPI==EPI_STORE)          C[idx] = v;
        else if (EPI==EPI_TANH)      C[idx] = tanhf(v + bias[col]);
        else if (EPI==EPI_LEAKY_ADD) C[idx] = leaky(v + bias[col]) + add[idx];
        else                         C[idx] += leaky(v + bias[col] + add[idx]);
      }
    }
  }
}

// ============ weight pre-split: W[K][N] fp32 -> Wt_hi/Wt_lo[Np][Kp] bf16 (transposed+padded) ============
struct WDesc { const float* w; u16 *th, *tl; int K, N, Kp, Np; };
struct WPack { WDesc d[12]; };
__global__ void split_w_k(WPack P)
{
  WDesc D = P.d[blockIdx.y];
  int gid = blockIdx.x*256 + threadIdx.x;
  int tot = D.Np * D.Kp;
  if (gid >= tot) return;
  int k = gid / D.Np, n = gid % D.Np;       // consecutive gid -> consecutive n -> coalesced reads
  float v = (k < D.K && n < D.N) ? D.w[(size_t)k*D.N + n] : 0.f;
  u16 h = f2bf(v);
  D.th[(size_t)n*D.Kp + k] = h;
  D.tl[(size_t)n*D.Kp + k] = f2bf(v - bf2f(h));
}

// ---------------- graph structure ----------------
// doubled edges: for e in [0,2E): src(e)=ei[e]; dst(e)= e<E ? ei[e+E] : ei[e-E]
__global__ void count_deg(const int* __restrict__ ei, int* __restrict__ deg, int E)
{
  int e = blockIdx.x*blockDim.x + threadIdx.x;
  if (e >= 2*E) return;
  int dst = (e < E) ? ei[e+E] : ei[e-E];
  atomicAdd(&deg[dst], 1);
}

__global__ void scan_rowptr(const int* __restrict__ deg, int* __restrict__ row_ptr, int n)
{
  __shared__ int sm[256];
  __shared__ int carry;
  int tid = threadIdx.x;
  if (tid==0) carry = 0;
  __syncthreads();
  for (int base=0; base<n; base+=256) {
    int idx = base + tid;
    int v = (idx < n) ? deg[idx] : 0;
    sm[tid] = v; __syncthreads();
    #pragma unroll
    for (int off=1; off<256; off<<=1) {
      int t = (tid >= off) ? sm[tid-off] : 0;
      __syncthreads();
      sm[tid] += t;
      __syncthreads();
    }
    if (idx < n) row_ptr[idx+1] = carry + sm[tid];
    __syncthreads();
    if (tid==255) carry += sm[255];
    __syncthreads();
  }
  if (tid==0) row_ptr[0] = 0;
}

__global__ void fill_csr(const int* __restrict__ ei, const int* __restrict__ row_ptr,
                         int* __restrict__ row_fill, int* __restrict__ col_src, int E)
{
  int e = blockIdx.x*blockDim.x + threadIdx.x;
  if (e >= 2*E) return;
  int src = ei[e];
  int dst = (e < E) ? ei[e+E] : ei[e-E];
  int pos = row_ptr[dst] + atomicAdd(&row_fill[dst], 1);
  col_src[pos] = src;
}

// guarded vector row load: v[j] = r[j] for c0+j<L else 0 (r already offset by c0)
template<int VW>
__device__ __forceinline__ void loadrow(const float* __restrict__ r, int c0, int L, float* v){
  if (c0 + VW <= L) {
    if (VW==4) *(float4*)v = *(const float4*)r;
    else       *(float2*)v = *(const float2*)r;
  } else {
    #pragma unroll
    for (int j=0;j<VW;j++) v[j] = (c0+j < L) ? r[j] : 0.f;
  }
}

// ---------------- l2norm + bf16 hi/lo split: x fp32 [NNODE][L] -> xh/xl [MP_NODE][Kp] ----------------
template<int VW>   // VW = Kp/64
__global__ __launch_bounds__(256)
void l2norm_split_k(const float* __restrict__ x, u16* __restrict__ xh, u16* __restrict__ xl, int L, int Kp)
{
  int row = (blockIdx.x*blockDim.x + threadIdx.x) >> 6;
  int lane = threadIdx.x & 63;
  if (row >= MP_NODE) return;
  int c0 = lane*VW;
  size_t ofs = (size_t)row*Kp + c0;
  if (row >= NNODE) {   // zero pad rows
    if (VW==4) { *(uint2*)&xh[ofs] = make_uint2(0,0); *(uint2*)&xl[ofs] = make_uint2(0,0); }
    else       { *(unsigned*)&xh[ofs] = 0; *(unsigned*)&xl[ofs] = 0; }
    return;
  }
  float v[VW];
  loadrow<VW>(x + (size_t)row*L + c0, c0, L, v);
  float ss = 0.f;
  #pragma unroll
  for (int j=0;j<VW;j++) ss += v[j]*v[j];
  #pragma unroll
  for (int o=32;o;o>>=1) ss += __shfl_xor(ss, o);
  float inv = 1.0f / fmaxf(sqrtf(ss), 1e-12f);
  u16 hs[VW], ls[VW];
  #pragma unroll
  for (int j=0;j<VW;j++){
    float val = (c0+j < L) ? v[j]*inv : 0.f;
    hs[j] = f2bf(val); ls[j] = f2bf(val - bf2f(hs[j]));
  }
  if (VW==4) { *(uint2*)&xh[ofs] = make_uint2(pack2(hs[0],hs[1]),pack2(hs[2],hs[3]));
               *(uint2*)&xl[ofs] = make_uint2(pack2(ls[0],ls[1]),pack2(ls[2],ls[3])); }
  else       { *(unsigned*)&xh[ofs] = pack2(hs[0],hs[1]); *(unsigned*)&xl[ofs] = pack2(ls[0],ls[1]); }
}

// ---------------- fused GAT edge logits + per-dst softmax (alpha in CSR order) ----------------
// one wave per dst node: dst row cached in regs; logits held in lanes (deg<=64; fallback spills via alpha buf)
template<int VW>
__global__ __launch_bounds__(256)
void gat_alpha_k(const float* __restrict__ xw, const int* __restrict__ row_ptr,
                 const int* __restrict__ col_src, const int* __restrict__ deg,
                 float* __restrict__ alpha, int L)
{
  int node = (blockIdx.x*blockDim.x + threadIdx.x) >> 6;
  int lane = threadIdx.x & 63;
  if (node >= NNODE) return;
  int s = row_ptr[node], e = row_ptr[node+1];
  int cnt = e - s;
  if (cnt == 0) return;
  int c0 = lane*VW;
  float dv[VW];
  loadrow<VW>(xw + (size_t)node*L + c0, c0, L, dv);
  float mylog = -INFINITY;
  for (int p=s; p<e; p++) {
    int src = col_src[p];
    float sv[VW];
    loadrow<VW>(xw + (size_t)src*L + c0, c0, L, sv);
    float dot = 0.f;
    #pragma unroll
    for (int j=0;j<VW;j++) dot = fmaf(dv[j], sv[j], dot);
    #pragma unroll
    for (int o=32;o;o>>=1) dot += __shfl_xor(dot, o);
    float t = dot / sqrtf((float)deg[src]);
    float gate = 1.0f/(1.0f + expf(-t));
    float lg = dot * gate;
    if (cnt <= 64) { if (lane == (p - s)) mylog = lg; }
    else           { if (lane == 0) alpha[p] = lg; }
  }
  if (cnt <= 64) {
    float m = mylog;
    #pragma unroll
    for (int o=32;o;o>>=1) m = fmaxf(m, __shfl_xor(m, o));
    float el = (lane < cnt) ? expf(mylog - m) : 0.f;
    float d = el;
    #pragma unroll
    for (int o=32;o;o>>=1) d += __shfl_xor(d, o);
    float inv = 1.0f / fmaxf(d, 1e-16f);
    if (lane < cnt) alpha[s + lane] = el * inv;
  } else {
    float m = -INFINITY;
    for (int p=s+lane;p<e;p+=64) m = fmaxf(m, alpha[p]);
    #pragma unroll
    for (int o=32;o;o>>=1) m = fmaxf(m, __shfl_xor(m, o));
    float d = 0.f;
    for (int p=s+lane;p<e;p+=64) d += expf(alpha[p]-m);
    #pragma unroll
    for (int o=32;o;o>>=1) d += __shfl_xor(d, o);
    float inv = 1.0f / fmaxf(d, 1e-16f);
    for (int p=s+lane;p<e;p+=64) alpha[p] = expf(alpha[p]-m)*inv;
  }
}

// ---------------- aggregate: h = leaky(l2norm(sum alpha*xw[src] + bias)) -> bf16 split [MP_NODE][Kp] ----------------
template<int VW>
__global__ __launch_bounds__(256)
void aggregate_k(const float* __restrict__ xw, const float* __restrict__ alpha,
                 const int* __restrict__ row_ptr, const int* __restrict__ col_src,
                 const float* __restrict__ bias, u16* __restrict__ hh, u16* __restrict__ hl,
                 int L, int Kp)
{
  int node = (blockIdx.x*blockDim.x + threadIdx.x) >> 6;
  int lane = threadIdx.x & 63;
  if (node >= MP_NODE) return;
  int c0 = lane*VW;
  size_t ofs = (size_t)node*Kp + c0;
  if (node >= NNODE) {
    if (VW==4) { *(uint2*)&hh[ofs] = make_uint2(0,0); *(uint2*)&hl[ofs] = make_uint2(0,0); }
    else       { *(unsigned*)&hh[ofs] = 0; *(unsigned*)&hl[ofs] = 0; }
    return;
  }
  float acc[VW] = {};
  int s = row_ptr[node], e = row_ptr[node+1];
  for (int p=s;p<e;p++) {
    float a = alpha[p];
    float v[VW];
    loadrow<VW>(xw + (size_t)col_src[p]*L + c0, c0, L, v);
    #pragma unroll
    for (int j=0;j<VW;j++) acc[j] = fmaf(a, v[j], acc[j]);
  }
  float t[VW], ss = 0.f;
  #pragma unroll
  for (int j=0;j<VW;j++){ int c = c0+j; t[j] = (c<L) ? acc[j]+bias[c] : 0.f; ss += t[j]*t[j]; }
  #pragma unroll
  for (int o=32;o;o>>=1) ss += __shfl_xor(ss, o);
  float inv = 1.0f / fmaxf(sqrtf(ss), 1e-12f);
  u16 hs[VW], ls[VW];
  #pragma unroll
  for (int j=0;j<VW;j++){
    float o2 = (c0+j < L) ? leaky(t[j]*inv) : 0.f;
    hs[j] = f2bf(o2); ls[j] = f2bf(o2 - bf2f(hs[j]));
  }
  if (VW==4) { *(uint2*)&hh[ofs] = make_uint2(pack2(hs[0],hs[1]),pack2(hs[2],hs[3]));
               *(uint2*)&hl[ofs] = make_uint2(pack2(ls[0],ls[1]),pack2(ls[2],ls[3])); }
  else       { *(unsigned*)&hh[ofs] = pack2(hs[0],hs[1]); *(unsigned*)&hl[ofs] = pack2(ls[0],ls[1]); }
}

// scores: out[0..1024)=pos, [1024..2048)=neg; rep holds 3*rep_true -> scale dot by 1/9
__global__ __launch_bounds__(256)
void score_k(const float* __restrict__ rep, const int* __restrict__ un,
             const int* __restrict__ pi, const int* __restrict__ ni, float* __restrict__ out)
{
  int wid = (blockIdx.x*blockDim.x + threadIdx.x) >> 6;
  int lane = threadIdx.x & 63;
  if (wid >= 2048) return;
  int i = wid & 1023;
  int isneg = wid >> 10;
  int u = un[i];
  int it = isneg ? ni[i] : pi[i];
  float p = rep[(size_t)u*64 + lane] * rep[(size_t)it*64 + lane];
  #pragma unroll
  for (int o=32;o;o>>=1) p += __shfl_xor(p, o);
  if (lane==0) out[isneg*1024 + i] = p * (1.0f/9.0f);
}

// ---------------- launch ----------------
static inline size_t align_up(size_t v){ return (v + 255) & ~(size_t)255; }
static inline int cdiv(int a, int b){ return (a + b - 1) / b; }

extern "C" void kernel_launch(void* const* d_in, const int* in_sizes, int n_in,
                              void* d_out, int out_size, void* d_ws, size_t ws_size,
                              hipStream_t stream)
{
  const int E  = in_sizes[31] / 2;   // 250000
  const int E2 = 2*E;

  // ---- workspace carve ----
  char* p = (char*)d_ws;
  auto carve = [&](size_t bytes){ char* r = p; p += align_up(bytes); return r; };
  float* x      = (float*)carve((size_t)NNODE*256*4);     // fp32 staging (pref|mlp out)
  float* xw     = (float*)carve((size_t)NNODE*256*4);
  u16*   xh     = (u16*)carve((size_t)MP_NODE*256*2);     // x (then h) hi split
  u16*   xl     = (u16*)carve((size_t)MP_NODE*256*2);
  float* xhat   = (float*)carve((size_t)NNODE*64*4);
  float* rep    = (float*)carve((size_t)NNODE*64*4);
  float* alpha  = (float*)carve((size_t)E2*4);
  int* deg      = (int*)carve((size_t)NNODE*4);
  int* row_ptr  = (int*)carve((size_t)(NNODE+1)*4);
  int* row_fill = (int*)carve((size_t)NNODE*4);
  int* col_src  = (int*)carve((size_t)E2*4);

  const int* ei = (const int*)d_in[31];
  const float* id_emb = (const float*)d_in[30];

  struct Mod { const float *feat,*pref,*mlp_w,*mlp_b,*conv_w,*conv_b,*lin_w,*lin_b,*g_w,*g_b;
               int Fd, L, Kpx, Kpf, NpL; };
  Mod md[3];
  for (int m=0;m<3;m++) {
    int b = m*10;
    md[m].feat   = (const float*)d_in[b+0];
    md[m].pref   = (const float*)d_in[b+1];
    md[m].mlp_w  = (const float*)d_in[b+2];
    md[m].mlp_b  = (const float*)d_in[b+3];
    md[m].conv_w = (const float*)d_in[b+4];
    md[m].conv_b = (const float*)d_in[b+5];
    md[m].lin_w  = (const float*)d_in[b+6];
    md[m].lin_b  = (const float*)d_in[b+7];
    md[m].g_w    = (const float*)d_in[b+8];
    md[m].g_b    = (const float*)d_in[b+9];
  }
  md[0].Fd=2048; md[0].L=256; md[0].Kpx=256; md[0].Kpf=2048; md[0].NpL=256;
  md[1].Fd=128;  md[1].L=128; md[1].Kpx=128; md[1].Kpf=128;  md[1].NpL=128;
  md[2].Fd=100;  md[2].L=100; md[2].Kpx=128; md[2].Kpf=128;  md[2].NpL=128;

  // per-modality weight split buffers (hi,lo) for mlp/conv/lin/g
  u16 *wmh[3],*wml[3],*wch[3],*wcl[3],*wlh[3],*wll[3],*wgh[3],*wgl[3];
  WPack P;
  int maxTot = 0;
  for (int m=0;m<3;m++) {
    const Mod& M_ = md[m];
    size_t smlp = (size_t)M_.NpL*M_.Kpf*2, sconv = (size_t)M_.NpL*M_.Kpx*2, slin = (size_t)64*M_.Kpx*2;
    wmh[m]=(u16*)carve(smlp); wml[m]=(u16*)carve(smlp);
    wch[m]=(u16*)carve(sconv); wcl[m]=(u16*)carve(sconv);
    wlh[m]=(u16*)carve(slin);  wll[m]=(u16*)carve(slin);
    wgh[m]=(u16*)carve(slin);  wgl[m]=(u16*)carve(slin);
    P.d[m*4+0] = { M_.mlp_w,  wmh[m], wml[m], M_.Fd, M_.L, M_.Kpf, M_.NpL };
    P.d[m*4+1] = { M_.conv_w, wch[m], wcl[m], M_.L,  M_.L, M_.Kpx, M_.NpL };
    P.d[m*4+2] = { M_.lin_w,  wlh[m], wll[m], M_.L,  64,   M_.Kpx, 64 };
    P.d[m*4+3] = { M_.g_w,    wgh[m], wgl[m], M_.L,  64,   M_.Kpx, 64 };
    for (int q=0;q<4;q++){ int t = P.d[m*4+q].Np*P.d[m*4+q].Kp; if (t>maxTot) maxTot=t; }
  }

  hipMemsetAsync(deg, 0, (size_t)NNODE*4, stream);
  hipMemsetAsync(row_fill, 0, (size_t)NNODE*4, stream);
  hipMemsetAsync(rep, 0, (size_t)NNODE*64*4, stream);

  { dim3 g(cdiv(maxTot,256), 12); split_w_k<<<g,256,0,stream>>>(P); }
  {
    int blocks = cdiv(E2, 256);
    count_deg<<<blocks,256,0,stream>>>(ei, deg, E);
    scan_rowptr<<<1,256,0,stream>>>(deg, row_ptr, NNODE);
    fill_csr<<<blocks,256,0,stream>>>(ei, row_ptr, row_fill, col_src, E);
  }

  for (int m=0;m<3;m++) {
    const Mod& M_ = md[m];
    const int L = M_.L;

    // x[0:NUSER) = pref ; x[NUSER:) = tanh(feat @ mlp_w + b)
    hipMemcpyAsync(x, M_.pref, (size_t)NUSER*L*4, hipMemcpyDeviceToDevice, stream);
    {
      dim3 g(M_.NpL/64, MP_USER/128);
      mgemm_k<EPI_TANH,false><<<g,256,0,stream>>>(M_.feat, nullptr, nullptr, wmh[m], wml[m],
          M_.mlp_b, nullptr, x + (size_t)NUSER*L, NUSER, L, M_.Fd, M_.Kpf);
    }
    // l2norm + split -> xh/xl
    if (M_.Kpx==256) l2norm_split_k<4><<<MP_NODE/4,256,0,stream>>>(x, xh, xl, L, M_.Kpx);
    else             l2norm_split_k<2><<<MP_NODE/4,256,0,stream>>>(x, xh, xl, L, M_.Kpx);
    // xw = x @ conv_w  (fp32 out, edge phase consumes it)
    {
      dim3 g(M_.NpL/64, MP_NODE/128);
      mgemm_k<EPI_STORE,true><<<g,256,0,stream>>>(nullptr, xh, xl, wch[m], wcl[m],
          nullptr, nullptr, xw, NNODE, L, L, M_.Kpx);
    }
    // xhat = leaky(x @ lin_w + b) + id_emb
    {
      dim3 g(1, MP_NODE/128);
      mgemm_k<EPI_LEAKY_ADD,true><<<g,256,0,stream>>>(nullptr, xh, xl, wlh[m], wll[m],
          M_.lin_b, id_emb, xhat, NNODE, 64, L, M_.Kpx);
    }
    // fused edge logits + softmax -> alpha (CSR order)
    if (L==256) gat_alpha_k<4><<<NNODE/4,256,0,stream>>>(xw, row_ptr, col_src, deg, alpha, L);
    else        gat_alpha_k<2><<<NNODE/4,256,0,stream>>>(xw, row_ptr, col_src, deg, alpha, L);
    // aggregate -> h (bf16 split, reuses xh/xl; conv+lin already consumed x)
    if (M_.Kpx==256) aggregate_k<4><<<MP_NODE/4,256,0,stream>>>(xw, alpha, row_ptr, col_src, M_.conv_b, xh, xl, L, M_.Kpx);
    else             aggregate_k<2><<<MP_NODE/4,256,0,stream>>>(xw, alpha, row_ptr, col_src, M_.conv_b, xh, xl, L, M_.Kpx);
    // rep += leaky(h @ g_w + g_b + xhat)
    {
      dim3 g(1, MP_NODE/128);
      mgemm_k<EPI_ACCUM,true><<<g,256,0,stream>>>(nullptr, xh, xl, wgh[m], wgl[m],
          M_.g_b, xhat, rep, NNODE, 64, L, M_.Kpx);
    }
  }

  score_k<<<cdiv(2048*64,256),256,0,stream>>>(rep, (const int*)d_in[32], (const int*)d_in[33],
                                              (const int*)d_in[34], (float*)d_out);
}